// Round 1
// baseline (25.679 us; speedup 1.0000x reference)
//
#include <hip/hip_runtime.h>

// LengthRegulator: B=16, T=512, D=384, DUR_MAX=8, MAX_OUT = 512*7 = 3584
// out[b, j, :] = x[b, src(b,j), :] if j < total(b) else 0
// where src(b,j) = searchsorted_right(cumsum(dur[b]), j)

#define B_  16
#define T_  512
#define D_  384
#define MAX_OUT_ 3584          // T*(DUR_MAX-1)
#define ROW_F4 (D_ / 4)        // 96 float4 per row

// ---------------------------------------------------------------------------
// Kernel 1: per-batch inclusive scan of dur + scatter inverse map.
// One block per batch, 512 threads (one per frame t).
// map[b*MAX_OUT + j] = t  for j in [ends[t]-dur[t], ends[t]), else -1.
// ---------------------------------------------------------------------------
__global__ __launch_bounds__(T_) void lr_scan_kernel(
    const int* __restrict__ dur, int* __restrict__ map) {
  const int b = blockIdx.x;
  const int t = threadIdx.x;           // 0..511
  const int d = dur[b * T_ + t];

  // wave-level inclusive scan (wave = 64 lanes)
  const int lane = t & 63;
  const int wave = t >> 6;             // 0..7
  int v = d;
  #pragma unroll
  for (int off = 1; off < 64; off <<= 1) {
    int n = __shfl_up(v, off, 64);
    if (lane >= off) v += n;
  }

  __shared__ int wsum[8];
  __shared__ int wpre[8];
  if (lane == 63) wsum[wave] = v;
  __syncthreads();
  if (t < 8) {
    int s = 0;
    for (int i = 0; i < t; ++i) s += wsum[i];   // 8 values, serial is fine
    wpre[t] = s;
  }
  __syncthreads();

  const int end_  = v + wpre[wave];    // inclusive cumsum = ends[t]  (<= MAX_OUT_)
  const int start = end_ - d;

  int* m = map + (size_t)b * MAX_OUT_;
  // init whole map row to -1 (7 entries per thread)
  for (int i = t; i < MAX_OUT_; i += T_) m[i] = -1;
  __syncthreads();
  // scatter: up to 7 writes per thread
  for (int k = start; k < end_; ++k) m[k] = t;
}

// ---------------------------------------------------------------------------
// Kernel 2: flat coalesced gather. One float4 per thread, exact grid.
// total float4 = B*MAX_OUT*96 = 5,505,024 -> 21504 blocks of 256.
// ---------------------------------------------------------------------------
__global__ __launch_bounds__(256) void lr_gather_kernel(
    const float4* __restrict__ x4, const int* __restrict__ map,
    float4* __restrict__ out4) {
  const unsigned gid = blockIdx.x * 256u + threadIdx.x;   // float4 index
  const unsigned row = gid / ROW_F4;                      // output row (b*MAX_OUT + j)
  const unsigned col = gid - row * ROW_F4;
  const int src = map[row];                               // broadcast across 96 lanes (L1)
  float4 v = make_float4(0.f, 0.f, 0.f, 0.f);
  if (src >= 0) {
    const unsigned b = row / MAX_OUT_;
    v = x4[(b * T_ + (unsigned)src) * ROW_F4 + col];
  }
  out4[gid] = v;
}

extern "C" void kernel_launch(void* const* d_in, const int* in_sizes, int n_in,
                              void* d_out, int out_size, void* d_ws, size_t ws_size,
                              hipStream_t stream) {
  const float* x   = (const float*)d_in[0];   // (B, T, D) fp32
  const int*   dur = (const int*)d_in[1];     // (B, T) int32
  float* out = (float*)d_out;                 // (B, MAX_OUT, D) fp32
  int* map = (int*)d_ws;                      // B*MAX_OUT ints = 229 KB

  lr_scan_kernel<<<B_, T_, 0, stream>>>(dur, map);

  const unsigned total_f4 = (unsigned)B_ * MAX_OUT_ * ROW_F4;   // 5,505,024
  lr_gather_kernel<<<total_f4 / 256, 256, 0, stream>>>(
      (const float4*)x, map, (float4*)out);
}

// Round 2
// 20.157 us; speedup vs baseline: 1.2740x; 1.2740x over previous
//
#include <hip/hip_runtime.h>

// LengthRegulator fused: B=16, T=512, D=384, DUR_MAX=8, MAX_OUT=3584
// out[b, j, :] = x[b, searchsorted_right(cumsum(dur[b]), j), :]  if j < total(b) else 0
//
// Single kernel: each block handles ROWS_PB output rows of one batch.
// The per-batch cumsum (512 ints) is recomputed per block — it's ~50 cycles of
// shuffle scan on a 2 KB L2-resident load, far cheaper than a separate kernel
// launch + global map round-trip.

#define B_       16
#define T_       512
#define D_       384
#define MAX_OUT_ 3584            // T*(DUR_MAX-1)
#define ROW_F4   (D_ / 4)        // 96 float4 per row
#define ROWS_PB  32              // rows per block -> 112 x 16 = 1792 blocks
#define F4_PB    (ROWS_PB * ROW_F4)   // 3072 float4 per block -> 12 per thread

__global__ __launch_bounds__(256) void lr_fused_kernel(
    const float4* __restrict__ x4, const int* __restrict__ dur,
    float4* __restrict__ out4) {
  const int b  = blockIdx.y;
  const int r0 = blockIdx.x * ROWS_PB;     // first output row of this block
  const int t  = threadIdx.x;              // 0..255

  __shared__ int ends[T_];                 // inclusive cumsum of dur[b]
  __shared__ int srcs[ROWS_PB];            // source frame per row (-1 = zero-fill)
  __shared__ int wsum[4];

  // ---- per-batch inclusive scan: 2 dur values per thread --------------------
  const int2 dd = ((const int2*)dur)[b * (T_ / 2) + t];  // dur[2t], dur[2t+1]
  int s = dd.x + dd.y;
  const int lane = t & 63;
  const int wave = t >> 6;                 // 0..3
  int v = s;
  #pragma unroll
  for (int off = 1; off < 64; off <<= 1) {
    int n = __shfl_up(v, off, 64);
    if (lane >= off) v += n;
  }
  if (lane == 63) wsum[wave] = v;
  __syncthreads();
  int wpre = 0;
  #pragma unroll
  for (int w = 0; w < 3; ++w)
    if (w < wave) wpre += wsum[w];
  const int e1 = v + wpre;                 // ends[2t+1]
  ends[2 * t]     = e1 - dd.y;             // ends[2t]
  ends[2 * t + 1] = e1;
  __syncthreads();

  // ---- searchsorted_right for this block's 32 rows --------------------------
  if (t < ROWS_PB) {
    const int j = r0 + t;
    int lo = 0;                            // ends up = #elements <= j (capped 511)
    #pragma unroll
    for (int step = 256; step > 0; step >>= 1)
      if (lo + step <= T_ && ends[lo + step - 1] <= j) lo += step;
    srcs[t] = (j < ends[T_ - 1]) ? lo : -1;
  }
  __syncthreads();

  // ---- flat coalesced copy: 12 float4 per thread ----------------------------
  const float4* __restrict__ xb = x4 + (size_t)b * T_ * ROW_F4;
  float4* __restrict__ ob = out4 + ((size_t)b * MAX_OUT_ + r0) * ROW_F4;
  #pragma unroll
  for (int k = 0; k < F4_PB / 256; ++k) {
    const int idx = k * 256 + t;           // 0..3071
    const int rl  = idx / ROW_F4;          // local row 0..31
    const int col = idx - rl * ROW_F4;     // 0..95
    const int src = srcs[rl];
    float4 val = make_float4(0.f, 0.f, 0.f, 0.f);
    if (src >= 0) val = xb[src * ROW_F4 + col];
    ob[idx] = val;
  }
}

extern "C" void kernel_launch(void* const* d_in, const int* in_sizes, int n_in,
                              void* d_out, int out_size, void* d_ws, size_t ws_size,
                              hipStream_t stream) {
  const float* x   = (const float*)d_in[0];   // (B, T, D) fp32
  const int*   dur = (const int*)d_in[1];     // (B, T) int32
  float* out = (float*)d_out;                 // (B, MAX_OUT, D) fp32

  dim3 grid(MAX_OUT_ / ROWS_PB, B_);          // (112, 16)
  lr_fused_kernel<<<grid, 256, 0, stream>>>(
      (const float4*)x, dur, (float4*)out);
}